// Round 7
// baseline (999.173 us; speedup 1.0000x reference)
//
#include <hip/hip_runtime.h>
#include <hip/hip_fp16.h>

#define SEQ   512
#define BATCH 64
#define EMB   256
#define HID   512

// recurrence W_hh split: 192 f16-pairs (384 cols) in named register vectors,
// 64 pairs (128 cols) in LDS
#define CR 192
#define CL 64
#define WLROW 68  // pairs per LDS row: 272B = 17 x 16B -> uniform 8/bank on b128

typedef _Float16 half2v  __attribute__((ext_vector_type(2)));
typedef _Float16 half8v  __attribute__((ext_vector_type(8)));   // 16B ds_read_b128
typedef _Float16 half32v __attribute__((ext_vector_type(32)));  // 16 VGPRs, named

__device__ __forceinline__ float dot2acc(half2v a, half2v b, float c) {
#if defined(__has_builtin)
#if __has_builtin(__builtin_amdgcn_fdot2)
  return __builtin_amdgcn_fdot2(a, b, c, false);
#else
  return fmaf((float)a[0], (float)b[0], fmaf((float)a[1], (float)b[1], c));
#endif
#else
  return fmaf((float)a[0], (float)b[0], fmaf((float)a[1], (float)b[1], c));
#endif
}

__device__ __forceinline__ float fast_tanh(float x) {
  x = fminf(fmaxf(x, -15.f), 15.f);
  float e = __expf(2.f * x);
  return (e - 1.f) / (e + 1.f);
}

// 32 f32 -> one named half32v (vector literal: no array, no dynamic indexing,
// guaranteed register-resident value)
__device__ __forceinline__ half32v load32f(const float* p) {
  const float4* q = reinterpret_cast<const float4*>(p);
  float4 v0=q[0],v1=q[1],v2=q[2],v3=q[3],v4=q[4],v5=q[5],v6=q[6],v7=q[7];
  half32v r = {
    (_Float16)v0.x,(_Float16)v0.y,(_Float16)v0.z,(_Float16)v0.w,
    (_Float16)v1.x,(_Float16)v1.y,(_Float16)v1.z,(_Float16)v1.w,
    (_Float16)v2.x,(_Float16)v2.y,(_Float16)v2.z,(_Float16)v2.w,
    (_Float16)v3.x,(_Float16)v3.y,(_Float16)v3.z,(_Float16)v3.w,
    (_Float16)v4.x,(_Float16)v4.y,(_Float16)v4.z,(_Float16)v4.w,
    (_Float16)v5.x,(_Float16)v5.y,(_Float16)v5.z,(_Float16)v5.w,
    (_Float16)v6.x,(_Float16)v6.y,(_Float16)v6.z,(_Float16)v6.w,
    (_Float16)v7.x,(_Float16)v7.y,(_Float16)v7.z,(_Float16)v7.w };
  return r;
}

// 4 dot2 ops: pairs [4M,4M+4) of wv against one broadcast half8v of h.
// Template M -> shufflevector indices are integer constant expressions.
template<int M>
__device__ __forceinline__ void dot4(half32v wv, half8v hv,
                                     float& a0, float& a1, float& a2, float& a3) {
  a0 = dot2acc(__builtin_shufflevector(wv, wv, 8*M+0, 8*M+1),
               __builtin_shufflevector(hv, hv, 0, 1), a0);
  a1 = dot2acc(__builtin_shufflevector(wv, wv, 8*M+2, 8*M+3),
               __builtin_shufflevector(hv, hv, 2, 3), a1);
  a2 = dot2acc(__builtin_shufflevector(wv, wv, 8*M+4, 8*M+5),
               __builtin_shufflevector(hv, hv, 4, 5), a2);
  a3 = dot2acc(__builtin_shufflevector(wv, wv, 8*M+6, 8*M+7),
               __builtin_shufflevector(hv, hv, 6, 7), a3);
}

// one 16-pair chunk (32 cols): 4 broadcast b128 reads + 16 dot2
__device__ __forceinline__ void dot_chunk(half32v wv, const half8v* hp, int qb,
                                          float& a0, float& a1, float& a2, float& a3) {
  dot4<0>(wv, hp[qb + 0], a0, a1, a2, a3);
  dot4<1>(wv, hp[qb + 1], a0, a1, a2, a3);
  dot4<2>(wv, hp[qb + 2], a0, a1, a2, a3);
  dot4<3>(wv, hp[qb + 3], a0, a1, a2, a3);
}

// X[t][b][j] = dot(emb[text[t][b]], W_ih[j]) + b_ih[j] + b_hh[j], stored f16.
// (unchanged from round 6: ~143us, not the bottleneck this round)
__global__ __launch_bounds__(512) void proj_kernel(
    const int* __restrict__ text, const float* __restrict__ emb,
    const float* __restrict__ Wih, const float* __restrict__ bih,
    const float* __restrict__ bhh, __half* __restrict__ X) {
  __shared__ __align__(16) __half se[BATCH][EMB];  // 32 KB
  __shared__ int stok[BATCH];

  const int t = blockIdx.x;
  const int j = threadIdx.x;

  if (j < BATCH) stok[j] = text[t * BATCH + j];
  __syncthreads();

  {
    const int r = j >> 3;
    const int c0 = (j & 7) * 32;
    const float4* src = reinterpret_cast<const float4*>(emb + (size_t)stok[r] * EMB + c0);
    half2v* rowp = reinterpret_cast<half2v*>(&se[r][0]);
#pragma unroll
    for (int q = 0; q < 8; ++q) {
      float4 v = src[q];
      half2v p0; p0[0] = (_Float16)v.x; p0[1] = (_Float16)v.y;
      half2v p1; p1[0] = (_Float16)v.z; p1[1] = (_Float16)v.w;
      rowp[c0 / 2 + 2 * q + 0] = p0;
      rowp[c0 / 2 + 2 * q + 1] = p1;
    }
  }
  __syncthreads();

  float acc[BATCH];
#pragma unroll
  for (int b = 0; b < BATCH; ++b) acc[b] = 0.f;

  for (int ec = 0; ec < EMB / 32; ++ec) {
    half2v wh[16];
    const float4* wp = reinterpret_cast<const float4*>(Wih + (size_t)j * EMB + ec * 32);
#pragma unroll
    for (int q = 0; q < 8; ++q) {
      float4 v = wp[q];
      wh[2 * q + 0][0] = (_Float16)v.x; wh[2 * q + 0][1] = (_Float16)v.y;
      wh[2 * q + 1][0] = (_Float16)v.z; wh[2 * q + 1][1] = (_Float16)v.w;
    }
#pragma unroll
    for (int b = 0; b < BATCH; ++b) {
      const half8v* ep = reinterpret_cast<const half8v*>(&se[b][ec * 32]);  // broadcast
      float a = acc[b];
#pragma unroll
      for (int r = 0; r < 4; ++r) {
        half8v ev = ep[r];
        a = dot2acc(wh[4*r+0], __builtin_shufflevector(ev, ev, 0, 1), a);
        a = dot2acc(wh[4*r+1], __builtin_shufflevector(ev, ev, 2, 3), a);
        a = dot2acc(wh[4*r+2], __builtin_shufflevector(ev, ev, 4, 5), a);
        a = dot2acc(wh[4*r+3], __builtin_shufflevector(ev, ev, 6, 7), a);
      }
      acc[b] = a;
    }
  }

  const float bias = bih[j] + bhh[j];
#pragma unroll
  for (int b = 0; b < BATCH; ++b)
    X[((size_t)t * BATCH + b) * HID + j] = __float2half(acc[b] + bias);
}

// One block per batch element. Thread j owns h[j]. W_hh row j cols [0,384)
// live in 12 NAMED half32v register vectors (no array -> nothing to spill via
// failed SROA; rounds 5/6 showed half2v w[192] went to scratch: VGPR=128,
// WRITE_SIZE=21MB on a 512-byte-output kernel). Cols [384,512) in LDS.
__global__
__attribute__((amdgpu_flat_work_group_size(512, 512), amdgpu_waves_per_eu(2, 2)))
void rnn_kernel(
    const __half* __restrict__ X, const float* __restrict__ Whh,
    const float* __restrict__ Wfc, const float* __restrict__ bfc,
    float* __restrict__ out) {
  __shared__ __align__(16) half2v Wl[HID * WLROW];   // 136 KB
  __shared__ __align__(16) half2v h2[2][HID / 2];    // 2 KB
  __shared__ float red[16];

  const int j = threadIdx.x;
  const int b = blockIdx.x;

  const float* wr = Whh + (size_t)j * HID;

  // register-resident W: cols [0,384) as 12 named 16-VGPR vectors
  half32v w0  = load32f(wr +   0), w1  = load32f(wr +  32), w2  = load32f(wr +  64);
  half32v w3  = load32f(wr +  96), w4  = load32f(wr + 128), w5  = load32f(wr + 160);
  half32v w6  = load32f(wr + 192), w7  = load32f(wr + 224), w8  = load32f(wr + 256);
  half32v w9  = load32f(wr + 288), w10 = load32f(wr + 320), w11 = load32f(wr + 352);

  // LDS-resident W: pairs [CR, CR+CL) -> Wl row j
#pragma unroll
  for (int c = 0; c < CL; ++c) {
    float2 v = reinterpret_cast<const float2*>(wr)[CR + c];
    half2v hh; hh[0] = (_Float16)v.x; hh[1] = (_Float16)v.y;
    Wl[j * WLROW + c] = hh;
  }
  if (j < HID / 2) {
    half2v z; z[0] = (_Float16)0.f; z[1] = (_Float16)0.f;
    h2[0][j] = z;
  }
  __syncthreads();

  const __half* Xp = X + (size_t)b * HID + j;  // stride per t = BATCH*HID
  float xv = __half2float(Xp[0]);
  float h = 0.f;
  int cur = 0;

  for (int t = 0; t < SEQ; ++t) {
    const int tn = (t < SEQ - 1) ? t + 1 : t;
    float xnext = __half2float(Xp[(size_t)tn * BATCH * HID]);

    const half8v* hp = reinterpret_cast<const half8v*>(&h2[cur][0]);
    const half8v* wl = reinterpret_cast<const half8v*>(&Wl[j * WLROW]);

    float a0 = 0.f, a1 = 0.f, a2 = 0.f, a3 = 0.f;
    dot_chunk(w0,  hp,  0, a0, a1, a2, a3);
    dot_chunk(w1,  hp,  4, a0, a1, a2, a3);
    dot_chunk(w2,  hp,  8, a0, a1, a2, a3);
    dot_chunk(w3,  hp, 12, a0, a1, a2, a3);
    dot_chunk(w4,  hp, 16, a0, a1, a2, a3);
    dot_chunk(w5,  hp, 20, a0, a1, a2, a3);
    dot_chunk(w6,  hp, 24, a0, a1, a2, a3);
    dot_chunk(w7,  hp, 28, a0, a1, a2, a3);
    dot_chunk(w8,  hp, 32, a0, a1, a2, a3);
    dot_chunk(w9,  hp, 36, a0, a1, a2, a3);
    dot_chunk(w10, hp, 40, a0, a1, a2, a3);
    dot_chunk(w11, hp, 44, a0, a1, a2, a3);

#pragma unroll
    for (int q = 0; q < CL / 4; ++q) {
      half8v hv = hp[CR / 4 + q];  // broadcast
      half8v wv = wl[q];           // per-lane b128, stride 272B (uniform banks)
      a0 = dot2acc(__builtin_shufflevector(wv, wv, 0, 1),
                   __builtin_shufflevector(hv, hv, 0, 1), a0);
      a1 = dot2acc(__builtin_shufflevector(wv, wv, 2, 3),
                   __builtin_shufflevector(hv, hv, 2, 3), a1);
      a2 = dot2acc(__builtin_shufflevector(wv, wv, 4, 5),
                   __builtin_shufflevector(hv, hv, 4, 5), a2);
      a3 = dot2acc(__builtin_shufflevector(wv, wv, 6, 7),
                   __builtin_shufflevector(hv, hv, 6, 7), a3);
    }

    float acc = ((a0 + a1) + (a2 + a3)) + xv;
    h = fast_tanh(acc);
    xv = xnext;

    // write new h to the other buffer; one barrier publishes it and protects
    // the buffer being read (reads hit cur, writes hit cur^1).
    reinterpret_cast<__half*>(&h2[cur ^ 1][0])[j] = __float2half(h);
    __syncthreads();
    cur ^= 1;
  }

  // final FC: out[b][o] = sum_j W_fc[o][j]*h[j] + b_fc[o]
  float c0 = Wfc[j] * h;
  float c1 = Wfc[HID + j] * h;
#pragma unroll
  for (int o = 32; o > 0; o >>= 1) {
    c0 += __shfl_down(c0, o, 64);
    c1 += __shfl_down(c1, o, 64);
  }
  const int wave = j >> 6;
  if ((j & 63) == 0) { red[wave] = c0; red[8 + wave] = c1; }
  __syncthreads();
  if (j == 0) {
    float s0 = 0.f, s1 = 0.f;
#pragma unroll
    for (int i = 0; i < 8; ++i) { s0 += red[i]; s1 += red[8 + i]; }
    out[b * 2 + 0] = s0 + bfc[0];
    out[b * 2 + 1] = s1 + bfc[1];
  }
}

extern "C" void kernel_launch(void* const* d_in, const int* in_sizes, int n_in,
                              void* d_out, int out_size, void* d_ws, size_t ws_size,
                              hipStream_t stream) {
  const int*   text = (const int*)d_in[0];
  const float* emb  = (const float*)d_in[1];
  const float* Wih  = (const float*)d_in[2];
  const float* Whh  = (const float*)d_in[3];
  const float* bih  = (const float*)d_in[4];
  const float* bhh  = (const float*)d_in[5];
  const float* Wfc  = (const float*)d_in[6];
  const float* bfc  = (const float*)d_in[7];
  float* outp = (float*)d_out;

  __half* X = (__half*)d_ws;  // SEQ*BATCH*HID f16 = 32 MiB

  proj_kernel<<<SEQ, 512, 0, stream>>>(text, emb, Wih, bih, bhh, X);
  rnn_kernel<<<BATCH, 512, 0, stream>>>(X, Whh, Wfc, bfc, outp);
}